// Round 1
// baseline (1295.961 us; speedup 1.0000x reference)
//
#include <hip/hip_runtime.h>
#include <hip/hip_bf16.h>
#include <stdint.h>

typedef uint32_t u32;
typedef uint16_t u16;
typedef __attribute__((ext_vector_type(8))) short short8;
typedef __attribute__((ext_vector_type(4))) float floatx4;

#define NH 16
#define HD 128
#define TSEQ 2048
#define NB 4
#define CM 2048
#define MROWS (NB*TSEQ)      // 8192
#define NQKV (3*CM)          // 6144

__device__ __forceinline__ u16 f2bf(float f) {
    union { float f; u32 u; } v; v.f = f;
    return (u16)((v.u + 0x7fffu + ((v.u >> 16) & 1u)) >> 16);
}

// ---------------- conversion kernels ----------------
__global__ __launch_bounds__(256) void convert_x_kernel(const float* __restrict__ in,
                                                        u16* __restrict__ out) {
    int idx = (blockIdx.x * 256 + threadIdx.x) * 8;
    float4 a = *(const float4*)(in + idx);
    float4 b = *(const float4*)(in + idx + 4);
    union { u16 s[8]; uint4 v; } o;
    o.s[0] = f2bf(a.x); o.s[1] = f2bf(a.y); o.s[2] = f2bf(a.z); o.s[3] = f2bf(a.w);
    o.s[4] = f2bf(b.x); o.s[5] = f2bf(b.y); o.s[6] = f2bf(b.z); o.s[7] = f2bf(b.w);
    *(uint4*)(out + idx) = o.v;
}

// in: [R][Cn] fp32 row-major  ->  out: [Cn][R] bf16 row-major
__global__ __launch_bounds__(256) void transpose_bf_kernel(const float* __restrict__ in,
                                                           u16* __restrict__ out,
                                                           int R, int Cn) {
    __shared__ float tile[32][33];
    int tx = threadIdx.x, ty = threadIdx.y;
    int c0 = blockIdx.x * 32, r0 = blockIdx.y * 32;
#pragma unroll
    for (int i = 0; i < 4; i++)
        tile[ty + i * 8][tx] = in[(size_t)(r0 + ty + i * 8) * Cn + c0 + tx];
    __syncthreads();
#pragma unroll
    for (int i = 0; i < 4; i++)
        out[(size_t)(c0 + ty + i * 8) * R + r0 + tx] = f2bf(tile[tx][ty + i * 8]);
}

// ---------------- QKV GEMM with fused RoPE + scatter ----------------
// A: x bf16 [8192][2048]; BT: W_qkv^T bf16 [6144][2048]
// q_ws/k_ws/v_ws: [b][h][t][d] bf16
__global__ __launch_bounds__(256, 2) void gemm_qkv_rope(const u16* __restrict__ A,
                                                        const u16* __restrict__ BT,
                                                        const float* __restrict__ sinp,
                                                        const float* __restrict__ cosp,
                                                        u16* __restrict__ q_ws,
                                                        u16* __restrict__ k_ws,
                                                        u16* __restrict__ v_ws) {
    __shared__ u16 As[128 * 40];
    __shared__ u16 Bs[128 * 40];
    int tid = threadIdx.x;
    int w = tid >> 6, lane = tid & 63, quad = lane >> 4, l15 = lane & 15;
    int mw = (w >> 1) * 64, nw = (w & 1) * 64;
    int rowBase = blockIdx.y * 128;
    int colBase = blockIdx.x * 128;

    floatx4 acc[4][4];
#pragma unroll
    for (int mi = 0; mi < 4; mi++)
#pragma unroll
        for (int ni = 0; ni < 4; ni++) acc[mi][ni] = (floatx4){0.f, 0.f, 0.f, 0.f};

    for (int k0 = 0; k0 < CM; k0 += 32) {
#pragma unroll
        for (int p = 0; p < 2; p++) {
            int idx = tid + p * 256;
            int r = idx >> 2, c8 = (idx & 3) * 8;
            *(uint4*)(&As[r * 40 + c8]) =
                *(const uint4*)(&A[(size_t)(rowBase + r) * CM + k0 + c8]);
            *(uint4*)(&Bs[r * 40 + c8]) =
                *(const uint4*)(&BT[(size_t)(colBase + r) * CM + k0 + c8]);
        }
        __syncthreads();
        short8 af[4], bf[4];
#pragma unroll
        for (int mi = 0; mi < 4; mi++)
            af[mi] = *(const short8*)(&As[(mw + mi * 16 + l15) * 40 + quad * 8]);
#pragma unroll
        for (int ni = 0; ni < 4; ni++)
            bf[ni] = *(const short8*)(&Bs[(nw + ni * 16 + l15) * 40 + quad * 8]);
#pragma unroll
        for (int mi = 0; mi < 4; mi++)
#pragma unroll
            for (int ni = 0; ni < 4; ni++)
                acc[mi][ni] = __builtin_amdgcn_mfma_f32_16x16x32_bf16(af[mi], bf[ni],
                                                                      acc[mi][ni], 0, 0, 0);
        __syncthreads();
    }

    const float inv_sqrt_hd = 0.08838834764831845f;
#pragma unroll
    for (int mi = 0; mi < 4; mi++) {
#pragma unroll
        for (int ni = 0; ni < 4; ni++) {
            int j = colBase + nw + ni * 16 + l15;
            int sec = j >> 11;
            int jj = j & 2047;
            int h = jj >> 7, d = jj & 127;
#pragma unroll
            for (int reg = 0; reg < 4; reg++) {
                int r = rowBase + mw + mi * 16 + quad * 4 + reg;
                int b = r >> 11, t = r & 2047;
                float v = acc[mi][ni][reg];
                float partner = __shfl_xor(v, 1, 64);
                size_t dsti = (size_t)((b * NH + h) * TSEQ + t) * HD + d;
                if (sec == 2) {
                    v_ws[dsti] = f2bf(v);
                } else {
                    float s = sinp[t * HD + d], c = cosp[t * HD + d];
                    float o = v * c + ((d & 1) ? partner * s : -partner * s);
                    if (sec == 0) o *= inv_sqrt_hd;
                    ((sec == 0) ? q_ws : k_ws)[dsti] = f2bf(o);
                }
            }
        }
    }
}

// ---------------- flash attention (causal) ----------------
// q/k/v: [b][h][t][d] bf16 (q pre-scaled by 1/sqrt(hd));  y: [b][t][h*HD+d] bf16
__global__ __launch_bounds__(256, 2) void attn_kernel(const u16* __restrict__ q_ws,
                                                      const u16* __restrict__ k_ws,
                                                      const u16* __restrict__ v_ws,
                                                      u16* __restrict__ y_bf) {
    __shared__ u16 Qs[64 * 136];
    __shared__ u16 Ks[64 * 136];
    __shared__ u16 Vt[128 * 72];   // V transposed: [d][key]
    __shared__ u16 Ps[64 * 72];    // P: [q_local][key]
    int tid = threadIdx.x;
    int w = tid >> 6, lane = tid & 63, quad = lane >> 4, l15 = lane & 15;
    int bh = blockIdx.x >> 5;
    int qt = 31 - (blockIdx.x & 31);   // big q-tiles (most work) launch first
    int b = bh >> 4, h = bh & 15;
    const u16* Qg = q_ws + (size_t)bh * TSEQ * HD;
    const u16* Kg = k_ws + (size_t)bh * TSEQ * HD;
    const u16* Vg = v_ws + (size_t)bh * TSEQ * HD;

#pragma unroll
    for (int p = 0; p < 4; p++) {
        int idx = tid + p * 256;
        int r = idx >> 4, c8 = (idx & 15) * 8;
        *(uint4*)(&Qs[r * 136 + c8]) = *(const uint4*)(&Qg[(size_t)(qt * 64 + r) * HD + c8]);
    }

    floatx4 O[8];
#pragma unroll
    for (int f = 0; f < 8; f++) O[f] = (floatx4){0.f, 0.f, 0.f, 0.f};
    float m_i[4], l_i[4];
#pragma unroll
    for (int g = 0; g < 4; g++) { m_i[g] = -3e38f; l_i[g] = 0.f; }

    for (int kt = 0; kt <= qt; kt++) {
        __syncthreads();
#pragma unroll
        for (int p = 0; p < 4; p++) {
            int idx = tid + p * 256;
            int r = idx >> 4, c8 = (idx & 15) * 8;
            *(uint4*)(&Ks[r * 136 + c8]) =
                *(const uint4*)(&Kg[(size_t)(kt * 64 + r) * HD + c8]);
            union { uint4 v; u16 s[8]; } tv;
            tv.v = *(const uint4*)(&Vg[(size_t)(kt * 64 + r) * HD + c8]);
#pragma unroll
            for (int jv = 0; jv < 8; jv++) Vt[(c8 + jv) * 72 + r] = tv.s[jv];
        }
        __syncthreads();

        // S = Q K^T  (rows: this wave's 16 queries; cols: 64 keys)
        floatx4 S[4];
#pragma unroll
        for (int nf = 0; nf < 4; nf++) {
            floatx4 a4 = (floatx4){0.f, 0.f, 0.f, 0.f};
#pragma unroll
            for (int kk = 0; kk < 4; kk++) {
                short8 a = *(const short8*)(&Qs[(w * 16 + l15) * 136 + kk * 32 + quad * 8]);
                short8 bb = *(const short8*)(&Ks[(nf * 16 + l15) * 136 + kk * 32 + quad * 8]);
                a4 = __builtin_amdgcn_mfma_f32_16x16x32_bf16(a, bb, a4, 0, 0, 0);
            }
            S[nf] = a4;
        }
        if (kt == qt) {
#pragma unroll
            for (int nf = 0; nf < 4; nf++) {
                int key = kt * 64 + nf * 16 + l15;
#pragma unroll
                for (int reg = 0; reg < 4; reg++) {
                    int query = qt * 64 + w * 16 + quad * 4 + reg;
                    if (key > query) S[nf][reg] = -3e38f;
                }
            }
        }
        // online softmax (each wave owns its 16 rows; row spread over 16 lanes)
        float alpha[4];
#pragma unroll
        for (int reg = 0; reg < 4; reg++) {
            float mx = S[0][reg];
#pragma unroll
            for (int nf = 1; nf < 4; nf++) mx = fmaxf(mx, S[nf][reg]);
#pragma unroll
            for (int off = 1; off < 16; off <<= 1) mx = fmaxf(mx, __shfl_xor(mx, off, 64));
            float m_new = fmaxf(m_i[reg], mx);
            alpha[reg] = __expf(m_i[reg] - m_new);
            m_i[reg] = m_new;
        }
        float rs[4] = {0.f, 0.f, 0.f, 0.f};
#pragma unroll
        for (int nf = 0; nf < 4; nf++) {
#pragma unroll
            for (int reg = 0; reg < 4; reg++) {
                float p = __expf(S[nf][reg] - m_i[reg]);
                rs[reg] += p;
                Ps[(w * 16 + quad * 4 + reg) * 72 + nf * 16 + l15] = f2bf(p);
            }
        }
#pragma unroll
        for (int reg = 0; reg < 4; reg++) {
            float r = rs[reg];
#pragma unroll
            for (int off = 1; off < 16; off <<= 1) r += __shfl_xor(r, off, 64);
            l_i[reg] = l_i[reg] * alpha[reg] + r;
        }
#pragma unroll
        for (int f = 0; f < 8; f++)
#pragma unroll
            for (int reg = 0; reg < 4; reg++) O[f][reg] *= alpha[reg];
        __syncthreads();   // safety: order Ps writes before A-frag reads
        // O += P V
#pragma unroll
        for (int f = 0; f < 8; f++) {
#pragma unroll
            for (int kk = 0; kk < 2; kk++) {
                short8 a = *(const short8*)(&Ps[(w * 16 + l15) * 72 + kk * 32 + quad * 8]);
                short8 bb = *(const short8*)(&Vt[(f * 16 + l15) * 72 + kk * 32 + quad * 8]);
                O[f] = __builtin_amdgcn_mfma_f32_16x16x32_bf16(a, bb, O[f], 0, 0, 0);
            }
        }
    }

#pragma unroll
    for (int f = 0; f < 8; f++) {
#pragma unroll
        for (int reg = 0; reg < 4; reg++) {
            int t = qt * 64 + w * 16 + quad * 4 + reg;
            int col = h * HD + f * 16 + l15;
            float val = O[f][reg] / l_i[reg];
            y_bf[(size_t)(b * TSEQ + t) * CM + col] = f2bf(val);
        }
    }
}

// ---------------- projection GEMM ----------------
// A: y bf16 [8192][2048]; BT: W_proj^T bf16 [2048][2048]; out fp32 [8192][2048]
__global__ __launch_bounds__(256, 2) void gemm_proj(const u16* __restrict__ A,
                                                    const u16* __restrict__ BT,
                                                    float* __restrict__ out) {
    __shared__ u16 As[128 * 40];
    __shared__ u16 Bs[128 * 40];
    int tid = threadIdx.x;
    int w = tid >> 6, lane = tid & 63, quad = lane >> 4, l15 = lane & 15;
    int mw = (w >> 1) * 64, nw = (w & 1) * 64;
    int rowBase = blockIdx.y * 128;
    int colBase = blockIdx.x * 128;

    floatx4 acc[4][4];
#pragma unroll
    for (int mi = 0; mi < 4; mi++)
#pragma unroll
        for (int ni = 0; ni < 4; ni++) acc[mi][ni] = (floatx4){0.f, 0.f, 0.f, 0.f};

    for (int k0 = 0; k0 < CM; k0 += 32) {
#pragma unroll
        for (int p = 0; p < 2; p++) {
            int idx = tid + p * 256;
            int r = idx >> 2, c8 = (idx & 3) * 8;
            *(uint4*)(&As[r * 40 + c8]) =
                *(const uint4*)(&A[(size_t)(rowBase + r) * CM + k0 + c8]);
            *(uint4*)(&Bs[r * 40 + c8]) =
                *(const uint4*)(&BT[(size_t)(colBase + r) * CM + k0 + c8]);
        }
        __syncthreads();
        short8 af[4], bf[4];
#pragma unroll
        for (int mi = 0; mi < 4; mi++)
            af[mi] = *(const short8*)(&As[(mw + mi * 16 + l15) * 40 + quad * 8]);
#pragma unroll
        for (int ni = 0; ni < 4; ni++)
            bf[ni] = *(const short8*)(&Bs[(nw + ni * 16 + l15) * 40 + quad * 8]);
#pragma unroll
        for (int mi = 0; mi < 4; mi++)
#pragma unroll
            for (int ni = 0; ni < 4; ni++)
                acc[mi][ni] = __builtin_amdgcn_mfma_f32_16x16x32_bf16(af[mi], bf[ni],
                                                                      acc[mi][ni], 0, 0, 0);
        __syncthreads();
    }

#pragma unroll
    for (int mi = 0; mi < 4; mi++) {
#pragma unroll
        for (int ni = 0; ni < 4; ni++) {
            int j = colBase + nw + ni * 16 + l15;
#pragma unroll
            for (int reg = 0; reg < 4; reg++) {
                int r = rowBase + mw + mi * 16 + quad * 4 + reg;
                out[(size_t)r * CM + j] = acc[mi][ni][reg];
            }
        }
    }
}

extern "C" void kernel_launch(void* const* d_in, const int* in_sizes, int n_in,
                              void* d_out, int out_size, void* d_ws, size_t ws_size,
                              hipStream_t stream) {
    const float* x      = (const float*)d_in[0];
    const float* sinp   = (const float*)d_in[1];
    const float* cosp   = (const float*)d_in[2];
    const float* W_qkv  = (const float*)d_in[3];
    const float* W_proj = (const float*)d_in[4];
    float* out = (float*)d_out;

    char* ws = (char*)d_ws;
    size_t off = 0;
    u16* x_bf   = (u16*)(ws + off); off += (size_t)MROWS * CM * 2;   // 32 MB (reused as y)
    u16* wqkvT  = (u16*)(ws + off); off += (size_t)NQKV * CM * 2;    // 24 MB
    u16* wprojT = (u16*)(ws + off); off += (size_t)CM * CM * 2;      //  8 MB
    u16* q_ws   = (u16*)(ws + off); off += (size_t)MROWS * CM * 2;   // 32 MB
    u16* k_ws   = (u16*)(ws + off); off += (size_t)MROWS * CM * 2;   // 32 MB
    u16* v_ws   = (u16*)(ws + off); off += (size_t)MROWS * CM * 2;   // 32 MB
    u16* y_bf   = x_bf;   // x dead after qkv GEMM

    convert_x_kernel<<<(MROWS * CM) / (256 * 8), 256, 0, stream>>>(x, x_bf);
    transpose_bf_kernel<<<dim3(NQKV / 32, CM / 32), dim3(32, 8), 0, stream>>>(W_qkv, wqkvT, CM, NQKV);
    transpose_bf_kernel<<<dim3(CM / 32, CM / 32), dim3(32, 8), 0, stream>>>(W_proj, wprojT, CM, CM);
    gemm_qkv_rope<<<dim3(NQKV / 128, MROWS / 128), 256, 0, stream>>>(x_bf, wqkvT, sinp, cosp,
                                                                     q_ws, k_ws, v_ws);
    attn_kernel<<<NB * NH * (TSEQ / 64), 256, 0, stream>>>(q_ws, k_ws, v_ws, y_bf);
    gemm_proj<<<dim3(CM / 128, MROWS / 128), 256, 0, stream>>>(y_bf, wprojT, out);
}

// Round 2
// 816.519 us; speedup vs baseline: 1.5872x; 1.5872x over previous
//
#include <hip/hip_runtime.h>
#include <hip/hip_bf16.h>
#include <stdint.h>

typedef uint32_t u32;
typedef uint16_t u16;
typedef __attribute__((ext_vector_type(8))) short short8;
typedef __attribute__((ext_vector_type(4))) float floatx4;

#define NH 16
#define HD 128
#define TSEQ 2048
#define NB 4
#define CM 2048
#define MROWS (NB*TSEQ)      // 8192
#define NQKV (3*CM)          // 6144

__device__ __forceinline__ u16 f2bf(float f) {
    union { float f; u32 u; } v; v.f = f;
    return (u16)((v.u + 0x7fffu + ((v.u >> 16) & 1u)) >> 16);
}

// ---------------- conversion kernels ----------------
__global__ __launch_bounds__(256) void convert_x_kernel(const float* __restrict__ in,
                                                        u16* __restrict__ out) {
    int idx = (blockIdx.x * 256 + threadIdx.x) * 8;
    float4 a = *(const float4*)(in + idx);
    float4 b = *(const float4*)(in + idx + 4);
    union { u16 s[8]; uint4 v; } o;
    o.s[0] = f2bf(a.x); o.s[1] = f2bf(a.y); o.s[2] = f2bf(a.z); o.s[3] = f2bf(a.w);
    o.s[4] = f2bf(b.x); o.s[5] = f2bf(b.y); o.s[6] = f2bf(b.z); o.s[7] = f2bf(b.w);
    *(uint4*)(out + idx) = o.v;
}

// in: [R][Cn] fp32 row-major  ->  out: [Cn][R] bf16 row-major
__global__ __launch_bounds__(256) void transpose_bf_kernel(const float* __restrict__ in,
                                                           u16* __restrict__ out,
                                                           int R, int Cn) {
    __shared__ float tile[32][33];
    int tx = threadIdx.x, ty = threadIdx.y;
    int c0 = blockIdx.x * 32, r0 = blockIdx.y * 32;
#pragma unroll
    for (int i = 0; i < 4; i++)
        tile[ty + i * 8][tx] = in[(size_t)(r0 + ty + i * 8) * Cn + c0 + tx];
    __syncthreads();
#pragma unroll
    for (int i = 0; i < 4; i++)
        out[(size_t)(c0 + ty + i * 8) * R + r0 + tx] = f2bf(tile[tx][ty + i * 8]);
}

// ---------------- QKV GEMM with fused RoPE + scatter ----------------
// A: x bf16 [8192][2048]; BT: W_qkv^T bf16 [6144][2048]
// q_ws/k_ws: [b][h][t][d] bf16;  v_ws: [b][h][d][t] bf16 (TRANSPOSED for attn)
__global__ __launch_bounds__(256, 2) void gemm_qkv_rope(const u16* __restrict__ A,
                                                        const u16* __restrict__ BT,
                                                        const float* __restrict__ sinp,
                                                        const float* __restrict__ cosp,
                                                        u16* __restrict__ q_ws,
                                                        u16* __restrict__ k_ws,
                                                        u16* __restrict__ v_ws) {
    __shared__ u16 As[128 * 40];
    __shared__ u16 Bs[128 * 40];
    int tid = threadIdx.x;
    int w = tid >> 6, lane = tid & 63, quad = lane >> 4, l15 = lane & 15;
    int mw = (w >> 1) * 64, nw = (w & 1) * 64;
    int rowBase = blockIdx.y * 128;
    int colBase = blockIdx.x * 128;

    floatx4 acc[4][4];
#pragma unroll
    for (int mi = 0; mi < 4; mi++)
#pragma unroll
        for (int ni = 0; ni < 4; ni++) acc[mi][ni] = (floatx4){0.f, 0.f, 0.f, 0.f};

    for (int k0 = 0; k0 < CM; k0 += 32) {
#pragma unroll
        for (int p = 0; p < 2; p++) {
            int idx = tid + p * 256;
            int r = idx >> 2, c8 = (idx & 3) * 8;
            *(uint4*)(&As[r * 40 + c8]) =
                *(const uint4*)(&A[(size_t)(rowBase + r) * CM + k0 + c8]);
            *(uint4*)(&Bs[r * 40 + c8]) =
                *(const uint4*)(&BT[(size_t)(colBase + r) * CM + k0 + c8]);
        }
        __syncthreads();
        short8 af[4], bf[4];
#pragma unroll
        for (int mi = 0; mi < 4; mi++)
            af[mi] = *(const short8*)(&As[(mw + mi * 16 + l15) * 40 + quad * 8]);
#pragma unroll
        for (int ni = 0; ni < 4; ni++)
            bf[ni] = *(const short8*)(&Bs[(nw + ni * 16 + l15) * 40 + quad * 8]);
#pragma unroll
        for (int mi = 0; mi < 4; mi++)
#pragma unroll
            for (int ni = 0; ni < 4; ni++)
                acc[mi][ni] = __builtin_amdgcn_mfma_f32_16x16x32_bf16(af[mi], bf[ni],
                                                                      acc[mi][ni], 0, 0, 0);
        __syncthreads();
    }

    const float inv_sqrt_hd = 0.08838834764831845f;
#pragma unroll
    for (int mi = 0; mi < 4; mi++) {
#pragma unroll
        for (int ni = 0; ni < 4; ni++) {
            int j = colBase + nw + ni * 16 + l15;
            int sec = j >> 11;
            int jj = j & 2047;
            int h = jj >> 7, d = jj & 127;
            if (sec == 2) {
                // V: pack 4 consecutive-t bf16 into one 8B store, transposed layout [b][h][d][t]
                int r0 = rowBase + mw + mi * 16 + quad * 4;
                int b = r0 >> 11, t0 = r0 & 2047;
                union { u16 s[4]; uint2 v; } pk;
#pragma unroll
                for (int reg = 0; reg < 4; reg++) pk.s[reg] = f2bf(acc[mi][ni][reg]);
                *(uint2*)(&v_ws[((size_t)(b * NH + h) * HD + d) * TSEQ + t0]) = pk.v;
            } else {
#pragma unroll
                for (int reg = 0; reg < 4; reg++) {
                    int r = rowBase + mw + mi * 16 + quad * 4 + reg;
                    int b = r >> 11, t = r & 2047;
                    float v = acc[mi][ni][reg];
                    float partner = __shfl_xor(v, 1, 64);
                    size_t dsti = (size_t)((b * NH + h) * TSEQ + t) * HD + d;
                    float s = sinp[t * HD + d], c = cosp[t * HD + d];
                    float o = v * c + ((d & 1) ? partner * s : -partner * s);
                    if (sec == 0) o *= inv_sqrt_hd;
                    ((sec == 0) ? q_ws : k_ws)[dsti] = f2bf(o);
                }
            }
        }
    }
}

// ---------------- flash attention (causal) ----------------
// q/k: [b][h][t][d] bf16 (q pre-scaled by 1/sqrt(hd)); vT: [b][h][d][t] bf16
// y: [b][t][h*HD+d] bf16
// Q-tile 128 (wave w owns rows w*32..w*32+31, 2 m-frags), K-tile 64.
__global__ __launch_bounds__(256, 2) void attn_kernel(const u16* __restrict__ q_ws,
                                                      const u16* __restrict__ k_ws,
                                                      const u16* __restrict__ vt_ws,
                                                      u16* __restrict__ y_bf) {
    __shared__ u16 Ks[64 * 136];   // [key][d]
    __shared__ u16 Vt[128 * 72];   // [d][key]
    __shared__ u16 Ps[128 * 72];   // [q_local][key]
    int tid = threadIdx.x;
    int w = tid >> 6, lane = tid & 63, quad = lane >> 4, l15 = lane & 15;
    int bh = blockIdx.x >> 4;
    int qt = 15 - (blockIdx.x & 15);   // big q-tiles first
    int b = bh >> 4, h = bh & 15;
    const u16* Qg = q_ws + (size_t)bh * TSEQ * HD;
    const u16* Kg = k_ws + (size_t)bh * TSEQ * HD;
    const u16* Vg = vt_ws + (size_t)bh * HD * TSEQ;

    // Q fragments in registers, loaded once (A-layout: m=l15, k=quad*8+j per 32-k chunk)
    short8 qf[2][4];
#pragma unroll
    for (int mi = 0; mi < 2; mi++)
#pragma unroll
        for (int kk = 0; kk < 4; kk++)
            qf[mi][kk] = *(const short8*)(&Qg[(size_t)(qt * 128 + w * 32 + mi * 16 + l15) * HD +
                                              kk * 32 + quad * 8]);

    floatx4 O[2][8];
#pragma unroll
    for (int mi = 0; mi < 2; mi++)
#pragma unroll
        for (int f = 0; f < 8; f++) O[mi][f] = (floatx4){0.f, 0.f, 0.f, 0.f};
    float m_i[2][4], l_i[2][4];
#pragma unroll
    for (int mi = 0; mi < 2; mi++)
#pragma unroll
        for (int g = 0; g < 4; g++) { m_i[mi][g] = -3e38f; l_i[mi][g] = 0.f; }

    int ktmax = 2 * qt + 1;
    for (int kt = 0; kt <= ktmax; kt++) {
        __syncthreads();
        // stage K tile [64][128] and V^T tile [128][64], vectorized 16B
#pragma unroll
        for (int p = 0; p < 4; p++) {
            int idx = tid + p * 256;
            int r = idx >> 4, c8 = (idx & 15) * 8;
            *(uint4*)(&Ks[r * 136 + c8]) =
                *(const uint4*)(&Kg[(size_t)(kt * 64 + r) * HD + c8]);
        }
#pragma unroll
        for (int p = 0; p < 4; p++) {
            int idx = tid + p * 256;
            int r = idx >> 3, c8 = (idx & 7) * 8;
            *(uint4*)(&Vt[r * 72 + c8]) =
                *(const uint4*)(&Vg[(size_t)r * TSEQ + kt * 64 + c8]);
        }
        __syncthreads();

        // S = Q K^T : rows = this wave's 32 queries, cols = 64 keys
        floatx4 S[2][4];
#pragma unroll
        for (int mi = 0; mi < 2; mi++)
#pragma unroll
            for (int nf = 0; nf < 4; nf++) {
                floatx4 a4 = (floatx4){0.f, 0.f, 0.f, 0.f};
#pragma unroll
                for (int kk = 0; kk < 4; kk++) {
                    short8 bb = *(const short8*)(&Ks[(nf * 16 + l15) * 136 + kk * 32 + quad * 8]);
                    a4 = __builtin_amdgcn_mfma_f32_16x16x32_bf16(qf[mi][kk], bb, a4, 0, 0, 0);
                }
                S[mi][nf] = a4;
            }
        if (kt >= 2 * qt) {   // diagonal region: mask key > query
#pragma unroll
            for (int mi = 0; mi < 2; mi++)
#pragma unroll
                for (int nf = 0; nf < 4; nf++) {
                    int key = kt * 64 + nf * 16 + l15;
#pragma unroll
                    for (int reg = 0; reg < 4; reg++) {
                        int query = qt * 128 + w * 32 + mi * 16 + quad * 4 + reg;
                        if (key > query) S[mi][nf][reg] = -3e38f;
                    }
                }
        }
        // online softmax (row = quad*4+reg, spread over 16 lanes)
#pragma unroll
        for (int mi = 0; mi < 2; mi++) {
            float alpha[4];
#pragma unroll
            for (int reg = 0; reg < 4; reg++) {
                float mx = S[mi][0][reg];
#pragma unroll
                for (int nf = 1; nf < 4; nf++) mx = fmaxf(mx, S[mi][nf][reg]);
#pragma unroll
                for (int off = 1; off < 16; off <<= 1) mx = fmaxf(mx, __shfl_xor(mx, off, 64));
                float m_new = fmaxf(m_i[mi][reg], mx);
                alpha[reg] = __expf(m_i[mi][reg] - m_new);
                m_i[mi][reg] = m_new;
            }
            float rs[4] = {0.f, 0.f, 0.f, 0.f};
#pragma unroll
            for (int nf = 0; nf < 4; nf++) {
#pragma unroll
                for (int reg = 0; reg < 4; reg++) {
                    float p = __expf(S[mi][nf][reg] - m_i[mi][reg]);
                    rs[reg] += p;
                    Ps[(w * 32 + mi * 16 + quad * 4 + reg) * 72 + nf * 16 + l15] = f2bf(p);
                }
            }
#pragma unroll
            for (int reg = 0; reg < 4; reg++) {
                float r = rs[reg];
#pragma unroll
                for (int off = 1; off < 16; off <<= 1) r += __shfl_xor(r, off, 64);
                l_i[mi][reg] = l_i[mi][reg] * alpha[reg] + r;
            }
#pragma unroll
            for (int f = 0; f < 8; f++)
#pragma unroll
                for (int reg = 0; reg < 4; reg++) O[mi][f][reg] *= alpha[reg];
        }
        // O += P V   (Ps rows produced & consumed by same wave -> no barrier needed)
#pragma unroll
        for (int mi = 0; mi < 2; mi++) {
            short8 pa[2];
#pragma unroll
            for (int kk = 0; kk < 2; kk++)
                pa[kk] = *(const short8*)(&Ps[(w * 32 + mi * 16 + l15) * 72 + kk * 32 + quad * 8]);
#pragma unroll
            for (int f = 0; f < 8; f++) {
#pragma unroll
                for (int kk = 0; kk < 2; kk++) {
                    short8 bb = *(const short8*)(&Vt[(f * 16 + l15) * 72 + kk * 32 + quad * 8]);
                    O[mi][f] = __builtin_amdgcn_mfma_f32_16x16x32_bf16(pa[kk], bb, O[mi][f], 0, 0, 0);
                }
            }
        }
    }

#pragma unroll
    for (int mi = 0; mi < 2; mi++)
#pragma unroll
        for (int f = 0; f < 8; f++) {
#pragma unroll
            for (int reg = 0; reg < 4; reg++) {
                int t = qt * 128 + w * 32 + mi * 16 + quad * 4 + reg;
                int col = h * HD + f * 16 + l15;
                float val = O[mi][f][reg] / l_i[mi][reg];
                y_bf[(size_t)(b * TSEQ + t) * CM + col] = f2bf(val);
            }
        }
}

// ---------------- projection GEMM ----------------
// A: y bf16 [8192][2048]; BT: W_proj^T bf16 [2048][2048]; out fp32 [8192][2048]
__global__ __launch_bounds__(256, 2) void gemm_proj(const u16* __restrict__ A,
                                                    const u16* __restrict__ BT,
                                                    float* __restrict__ out) {
    __shared__ u16 As[128 * 40];
    __shared__ u16 Bs[128 * 40];
    int tid = threadIdx.x;
    int w = tid >> 6, lane = tid & 63, quad = lane >> 4, l15 = lane & 15;
    int mw = (w >> 1) * 64, nw = (w & 1) * 64;
    int rowBase = blockIdx.y * 128;
    int colBase = blockIdx.x * 128;

    floatx4 acc[4][4];
#pragma unroll
    for (int mi = 0; mi < 4; mi++)
#pragma unroll
        for (int ni = 0; ni < 4; ni++) acc[mi][ni] = (floatx4){0.f, 0.f, 0.f, 0.f};

    for (int k0 = 0; k0 < CM; k0 += 32) {
#pragma unroll
        for (int p = 0; p < 2; p++) {
            int idx = tid + p * 256;
            int r = idx >> 2, c8 = (idx & 3) * 8;
            *(uint4*)(&As[r * 40 + c8]) =
                *(const uint4*)(&A[(size_t)(rowBase + r) * CM + k0 + c8]);
            *(uint4*)(&Bs[r * 40 + c8]) =
                *(const uint4*)(&BT[(size_t)(colBase + r) * CM + k0 + c8]);
        }
        __syncthreads();
        short8 af[4], bf[4];
#pragma unroll
        for (int mi = 0; mi < 4; mi++)
            af[mi] = *(const short8*)(&As[(mw + mi * 16 + l15) * 40 + quad * 8]);
#pragma unroll
        for (int ni = 0; ni < 4; ni++)
            bf[ni] = *(const short8*)(&Bs[(nw + ni * 16 + l15) * 40 + quad * 8]);
#pragma unroll
        for (int mi = 0; mi < 4; mi++)
#pragma unroll
            for (int ni = 0; ni < 4; ni++)
                acc[mi][ni] = __builtin_amdgcn_mfma_f32_16x16x32_bf16(af[mi], bf[ni],
                                                                      acc[mi][ni], 0, 0, 0);
        __syncthreads();
    }

#pragma unroll
    for (int mi = 0; mi < 4; mi++) {
#pragma unroll
        for (int ni = 0; ni < 4; ni++) {
            int j = colBase + nw + ni * 16 + l15;
#pragma unroll
            for (int reg = 0; reg < 4; reg++) {
                int r = rowBase + mw + mi * 16 + quad * 4 + reg;
                out[(size_t)r * CM + j] = acc[mi][ni][reg];
            }
        }
    }
}

extern "C" void kernel_launch(void* const* d_in, const int* in_sizes, int n_in,
                              void* d_out, int out_size, void* d_ws, size_t ws_size,
                              hipStream_t stream) {
    const float* x      = (const float*)d_in[0];
    const float* sinp   = (const float*)d_in[1];
    const float* cosp   = (const float*)d_in[2];
    const float* W_qkv  = (const float*)d_in[3];
    const float* W_proj = (const float*)d_in[4];
    float* out = (float*)d_out;

    char* ws = (char*)d_ws;
    size_t off = 0;
    u16* x_bf   = (u16*)(ws + off); off += (size_t)MROWS * CM * 2;   // 32 MB (reused as y)
    u16* wqkvT  = (u16*)(ws + off); off += (size_t)NQKV * CM * 2;    // 24 MB
    u16* wprojT = (u16*)(ws + off); off += (size_t)CM * CM * 2;      //  8 MB
    u16* q_ws   = (u16*)(ws + off); off += (size_t)MROWS * CM * 2;   // 32 MB
    u16* k_ws   = (u16*)(ws + off); off += (size_t)MROWS * CM * 2;   // 32 MB
    u16* v_ws   = (u16*)(ws + off); off += (size_t)MROWS * CM * 2;   // 32 MB (transposed [b][h][d][t])
    u16* y_bf   = x_bf;   // x dead after qkv GEMM

    convert_x_kernel<<<(MROWS * CM) / (256 * 8), 256, 0, stream>>>(x, x_bf);
    transpose_bf_kernel<<<dim3(NQKV / 32, CM / 32), dim3(32, 8), 0, stream>>>(W_qkv, wqkvT, CM, NQKV);
    transpose_bf_kernel<<<dim3(CM / 32, CM / 32), dim3(32, 8), 0, stream>>>(W_proj, wprojT, CM, CM);
    gemm_qkv_rope<<<dim3(NQKV / 128, MROWS / 128), 256, 0, stream>>>(x_bf, wqkvT, sinp, cosp,
                                                                     q_ws, k_ws, v_ws);
    attn_kernel<<<NB * NH * (TSEQ / 128), 256, 0, stream>>>(q_ws, k_ws, v_ws, y_bf);
    gemm_proj<<<dim3(CM / 128, MROWS / 128), 256, 0, stream>>>(y_bf, wprojT, out);
}